// Round 2
// 60.789 us; speedup vs baseline: 1.0032x; 1.0032x over previous
//
#include <hip/hip_runtime.h>

// Fused shift/roll/unfold/conv (all f32, f32 LDS intermediates):
//   r[h,k,o,l] = gate_b(k,o)*x[l,h,widx_b(k,o)] + gate_a(k,o)*x[128+l,h,widx_a(k,o)]
//   y[i,n,o]   = sum_{j,k,l} r[n+j-1,k,o,l] * w[i,j,k,l]
//
// Grid (14 n, 16 ig) = 224 blocks (single round). Block 512 (8 waves), 16 i/block.
// Wave split: wv = (ig2<<1)|oh ; ig2 = 4-i group (4 i in regs), oh = o-half (7 o's).
//   -> per-wave LDS rs reads halve vs 2-i/wave (35 instead of 70 wave-loads),
//      phase-2 LDS pipe traffic 480KB -> 240KB/block (it was the dominant cost).
// Phase 1 (384 thr): thread=(j,l): x rows (global, L2-resident) -> regs -> 42 static r -> rs f32.
// Phase 2: q-split across lanes (q = qi*256+lane*4, tail 1024+lane*2); w in registers.
//          parts row stride 64 with 4-float rotation p=(lane+4*row)&63 -> conflict-min both ways.
// Phase 3 (224 thr = 224 outputs): float4 reduce at minimum 8 words/bank.

#define PSTR 64

__global__ __launch_bounds__(512) void fused_shiftconv(
    const float* __restrict__ x,    // (256,14,14)
    const float* __restrict__ w,    // (256,3,3,128): i*1152 + (j*3+k)*128 + l
    float* __restrict__ out)        // (256,14,14)
{
    __shared__ __align__(16) float rs[126 * 128];      // 64512 B f32 r-slice
    __shared__ __align__(16) float parts[224 * PSTR];  // 57344 B rotated lane-partials

    const int n    = blockIdx.x;
    const int ig   = blockIdx.y;          // 0..15, 16 i per block
    const int t    = threadIdx.x;
    const int lane = t & 63;
    const int wv   = t >> 6;              // 0..7
    const int ig2  = wv >> 1;             // 0..3 : which 4-i group this wave owns
    const int oh   = wv & 1;              // 0..1 : which half of o this wave owns

    // ---- w staging into registers (coalesced, overlaps phase 1) ----
    // 4 i per wave; the (ig2, oh=0/1) wave pair loads the same 4 rows (L2-resident).
    const float* wbase = w + (ig * 16 + ig2 * 4) * 1152;
    float4 wq[4][4];
    float2 wt[4];
    #pragma unroll
    for (int ii = 0; ii < 4; ++ii) {
        const float* wp = wbase + ii * 1152;
        #pragma unroll
        for (int qi = 0; qi < 4; ++qi)
            wq[ii][qi] = *(const float4*)(wp + qi * 256 + lane * 4);
        wt[ii] = *(const float2*)(wp + 1024 + lane * 2);
    }

    // ---- Phase 1: build rs (384 threads; thread = (j = t>>7, l = t&127)) ----
    if (t < 384) {
        const int j = t >> 7;
        const int l = t & 127;
        const int h = n + j - 1;
        float xlo[14], xhi[14];
        if ((unsigned)h < 14u) {                    // wave-uniform branch
            const float* p0 = x + l * 196 + h * 14;
            const float* p1 = x + (128 + l) * 196 + h * 14;
            #pragma unroll
            for (int wi = 0; wi < 14; wi += 2) {
                float2 a = *(const float2*)(p0 + wi);
                float2 b = *(const float2*)(p1 + wi);
                xlo[wi] = a.x; xlo[wi + 1] = a.y;
                xhi[wi] = b.x; xhi[wi + 1] = b.y;
            }
        } else {
            #pragma unroll
            for (int wi = 0; wi < 14; ++wi) { xlo[wi] = 0.f; xhi[wi] = 0.f; }
        }
        // 42 (k,o) values, all indices compile-time after unroll
        #pragma unroll
        for (int k = 0; k < 3; ++k) {
            #pragma unroll
            for (int o = 0; o < 14; ++o) {
                float val = 0.f;
                const int wb = o + k - 1;                 // B-term gate/index
                if (wb >= 0 && wb < 14) val += xlo[wb ? wb - 1 : 13];
                const int v  = o ? o - 1 : 13;            // A-term gate/index
                const int wa = v + k - 1;
                if (wa >= 0 && wa < 14) val += xhi[wa ? wa - 1 : 13];
                rs[((j * 3 + k) * 14 + o) * 128 + l] = val;
            }
        }
    }
    __syncthreads();

    // ---- Phase 2: per o (7 per wave), per-lane partial dots, 4 i per wave ----
    const int rbl   = (lane & 31) * 4;     // l base for qi chunks
    const int jkhi  = lane >> 5;           // 0/1: jk = qi*2 + jkhi
    #pragma unroll 2
    for (int op = 0; op < 7; ++op) {
        const int o  = oh * 7 + op;
        const int ro = o * 128;
        float4 rv0 = *(const float4*)(rs + (0 + jkhi) * 1792 + ro + rbl);
        float4 rv1 = *(const float4*)(rs + (2 + jkhi) * 1792 + ro + rbl);
        float4 rv2 = *(const float4*)(rs + (4 + jkhi) * 1792 + ro + rbl);
        float4 rv3 = *(const float4*)(rs + (6 + jkhi) * 1792 + ro + rbl);
        float2 rt  = *(const float2*)(rs + (112 + o) * 128 + lane * 2);
        #pragma unroll
        for (int ii = 0; ii < 4; ++ii) {
            float a0, a1;
            a0  = rv0.x * wq[ii][0].x + rv0.y * wq[ii][0].y + rv0.z * wq[ii][0].z + rv0.w * wq[ii][0].w;
            a1  = rv1.x * wq[ii][1].x + rv1.y * wq[ii][1].y + rv1.z * wq[ii][1].z + rv1.w * wq[ii][1].w;
            a0 += rv2.x * wq[ii][2].x + rv2.y * wq[ii][2].y + rv2.z * wq[ii][2].z + rv2.w * wq[ii][2].w;
            a1 += rv3.x * wq[ii][3].x + rv3.y * wq[ii][3].y + rv3.z * wq[ii][3].z + rv3.w * wq[ii][3].w;
            a0 += rt.x * wt[ii].x + rt.y * wt[ii].y;
            const int row = (ig2 * 4 + ii) * 14 + o;      // bijective over 224 rows
            parts[row * PSTR + ((lane + 4 * row) & 63)] = a0 + a1;   // rotated: conflict-free
        }
    }
    __syncthreads();

    // ---- Phase 3: reduce 64 rotated lane-partials per output (224 thr = 224 outputs) ----
    if (t < 224) {
        const float* pr = parts + t * PSTR;
        float s0 = 0.f, s1 = 0.f;
        #pragma unroll
        for (int g = 0; g < 16; g += 2) {
            float4 v0 = *(const float4*)(pr + ((4 * g + 4 * t) & 63));        // min 8 words/bank
            float4 v1 = *(const float4*)(pr + ((4 * (g + 1) + 4 * t) & 63));
            s0 += v0.x + v0.y + v0.z + v0.w;
            s1 += v1.x + v1.y + v1.z + v1.w;
        }
        const int il = t / 14;                 // i_local 0..15
        const int o  = t - il * 14;
        const int i  = ig * 16 + il;
        out[(i * 14 + n) * 14 + o] = s0 + s1;
    }
}

extern "C" void kernel_launch(void* const* d_in, const int* in_sizes, int n_in,
                              void* d_out, int out_size, void* d_ws, size_t ws_size,
                              hipStream_t stream) {
    const float* x = (const float*)d_in[0];  // 256*14*14
    const float* w = (const float*)d_in[1];  // 256*3*3*128
    float* out = (float*)d_out;              // 256*14*14
    dim3 grid(14, 16);
    fused_shiftconv<<<grid, 512, 0, stream>>>(x, w, out);
}